// Round 12
// baseline (112.801 us; speedup 1.0000x reference)
//
#include <hip/hip_runtime.h>
#include <stdint.h>

// Problem: x0,y0 [B=64, C=36, L=4096] float32.
// out = y0 * (mean(x0,-1) + mean(y0,-1)), float32.
// Memory-bound: 113.2 MB minimal traffic -> ~17.5-18 us floor at the
// 6.35-6.45 TB/s the harness's own 256 MiB fills demonstrate.
//
// Harness note: dur_us carries ~83-84 us of workspace-poison fills
// (2 x 256 MiB fillBuffer @ ~41.5-42 us) inside the timed graph.
// Residual ladder: 4 indep waves 28; 9 w/CU 26; 18 w/CU zero-tail 24.7;
// 32 w/CU (+tail) 24.0. => occupancy saturates ~18+ waves/CU; the
// zero-tail grid did NOT help (tail theory falsified round 10).
//
// This round (pre-committed probe): round-9 config (256 thr/row, best
// twice-measured) + NONTEMPORAL LOADS. x,y are each read exactly once;
// NT loads skip L2/L3 allocation so 75.5 MB of dead-on-arrival lines
// don't pay fill/evict overhead against the demand stream. NT stores
// already in place. If flat: declare roofline.

typedef float v4f __attribute__((ext_vector_type(4)));

#define LL    4096
#define ROWS  (64 * 36)         // 2304 blocks, one per (b,c) row
#define BLOCK 256               // 4 waves/row
#define F4T   (LL / 4 / BLOCK)  // 4 float4 per thread

__global__ __launch_bounds__(BLOCK, 8) void spo2_rowscale(
    const float* __restrict__ x,
    const float* __restrict__ y,
    float* __restrict__ out)
{
    const int tid  = threadIdx.x;
    const size_t base = (size_t)blockIdx.x * LL;

    const v4f* xv = (const v4f*)(x + base);
    const v4f* yv = (const v4f*)(y + base);
    v4f*       ov = (v4f*)(out + base);

    // Issue ALL loads before any dependent math (max MLP per wave).
    // Nontemporal: single-use streaming data, skip cache allocation.
    v4f xr[F4T], yr[F4T];
#pragma unroll
    for (int i = 0; i < F4T; ++i)
        xr[i] = __builtin_nontemporal_load(xv + tid + i * BLOCK);
#pragma unroll
    for (int i = 0; i < F4T; ++i)
        yr[i] = __builtin_nontemporal_load(yv + tid + i * BLOCK);

    // Two independent accumulators.
    float sx = 0.f, sy = 0.f;
#pragma unroll
    for (int i = 0; i < F4T; ++i) {
        sx += xr[i].x + xr[i].y + xr[i].z + xr[i].w;
        sy += yr[i].x + yr[i].y + yr[i].z + yr[i].w;
    }
    float s = sx + sy;

    // Wave-64 xor butterfly: all lanes end with the wave partial.
#pragma unroll
    for (int off = 32; off > 0; off >>= 1)
        s += __shfl_xor(s, off, 64);

    // Cross-wave combine: 4 floats in LDS, one barrier, broadcast reads.
    __shared__ float rs[BLOCK / 64];
    const int wid  = tid >> 6;
    const int lane = tid & 63;
    if (lane == 0) rs[wid] = s;
    __syncthreads();

    float total = 0.f;
#pragma unroll
    for (int w = 0; w < BLOCK / 64; ++w) total += rs[w];
    const float scale = total * (1.0f / (float)LL);

    // Nontemporal stores: out is never re-read, skip L2 allocation.
#pragma unroll
    for (int i = 0; i < F4T; ++i) {
        v4f o = yr[i] * scale;
        __builtin_nontemporal_store(o, ov + tid + i * BLOCK);
    }
}

extern "C" void kernel_launch(void* const* d_in, const int* in_sizes, int n_in,
                              void* d_out, int out_size, void* d_ws, size_t ws_size,
                              hipStream_t stream) {
    const float* x = (const float*)d_in[0];
    const float* y = (const float*)d_in[1];
    float* out = (float*)d_out;
    spo2_rowscale<<<ROWS, BLOCK, 0, stream>>>(x, y, out);
}